// Round 2
// baseline (72.120 us; speedup 1.0000x reference)
//
#include <hip/hip_runtime.h>

// DAG reachability closure from node 0. N=8192 nodes, each with left/right
// child in [-1, N). Reference = N relaxation steps == transitive closure.
// Single-workgroup BFS-to-fixpoint entirely in LDS:
//   - left/right staged in LDS (64 KB)
//   - reachable set = 1024-byte bitmask in LDS
//   - thread t owns nodes [8t, 8t+8): private "expanded" byte makes total
//     expansion work O(N) (each node's edges pushed exactly once)
//   - LDS atomicOr scatters child bits; LDS flag detects fixpoint
// Output: bool mask -> INT32 0/1 (harness reads bool output as int32 —
// round-1 absmax was exactly bitcast(1.0f)-1).

#define NMAX 8192
#define BLK  1024

__global__ __launch_bounds__(BLK) void dag_reach_kernel(
    const int* __restrict__ left,
    const int* __restrict__ right,
    int* __restrict__ out,
    int n)
{
    __shared__ int sL[NMAX];
    __shared__ int sR[NMAX];
    __shared__ unsigned int reach[NMAX / 32];   // 256 words = 8192 bits
    __shared__ int s_changed;

    const int tid = threadIdx.x;

    // Stage edges into LDS (coalesced).
    for (int i = tid; i < n; i += BLK) {
        sL[i] = left[i];
        sR[i] = right[i];
    }
    for (int i = tid; i < NMAX / 32; i += BLK) reach[i] = 0u;
    __syncthreads();
    if (tid == 0) reach[0] = 1u;          // node 0 always reachable

    unsigned int myExp = 0u;              // expanded bits for nodes base..base+7
    const int base = tid * 8;
    __syncthreads();

    while (true) {
        if (tid == 0) s_changed = 0;
        __syncthreads();

        // My 8 bits live in byte (tid&3) of word (tid>>2).
        unsigned int word = reach[tid >> 2];
        unsigned int pend = ((word >> ((tid & 3) * 8)) & 0xFFu) & ~myExp;

        if (pend && base < n) {
            s_changed = 1;                // benign same-value race on LDS
            myExp |= pend;
            while (pend) {
                int b = __ffs(pend) - 1;
                pend &= pend - 1;
                int node = base + b;
                if (node < n) {
                    int l = sL[node];
                    int r = sR[node];
                    if (l >= 0) atomicOr(&reach[l >> 5], 1u << (l & 31));
                    if (r >= 0) atomicOr(&reach[r >> 5], 1u << (r & 31));
                }
            }
        }
        __syncthreads();
        if (!s_changed) break;            // fixpoint: no node expanded this pass
    }

    // Write bool mask as int32 0/1 (coalesced).
    for (int i = tid; i < n; i += BLK) {
        out[i] = (int)((reach[i >> 5] >> (i & 31)) & 1u);
    }
}

extern "C" void kernel_launch(void* const* d_in, const int* in_sizes, int n_in,
                              void* d_out, int out_size, void* d_ws, size_t ws_size,
                              hipStream_t stream)
{
    // inputs: 0 = thresholds (f32, UNUSED by reference), 1 = left (i32), 2 = right (i32)
    const int* left  = (const int*)d_in[1];
    const int* right = (const int*)d_in[2];
    int* out = (int*)d_out;
    const int n = in_sizes[1];

    dag_reach_kernel<<<1, BLK, 0, stream>>>(left, right, out, n);
}